// Round 1
// baseline (1167.246 us; speedup 1.0000x reference)
//
#include <hip/hip_runtime.h>
#include <hip/hip_bf16.h>

#define N_NODES 100000
#define N_EDGES 1600000
#define N_FEAT 128
#define N_HID 128
#define N_CLASS 10
#define N_GRAPHS 512
// 1/sqrt(1 + 1e-5)
#define BN_RSQRT 0.9999950000374997f

// ---------------- degree / histogram ----------------
__global__ void deg_kernel(const int* __restrict__ dst, int* __restrict__ deg, int n) {
    int e = blockIdx.x * blockDim.x + threadIdx.x;
    if (e < n) atomicAdd(&deg[dst[e]], 1);
}

__global__ void bhist_kernel(const int* __restrict__ batch, int* __restrict__ cnt, int n) {
    int i = blockIdx.x * blockDim.x + threadIdx.x;
    if (i < n) atomicAdd(&cnt[batch[i]], 1);
}

// exclusive scan of in[0..n) -> out[0..n], out[n] = total. Single block, 1024 threads.
__global__ void scan_exclusive(const int* __restrict__ in, int* __restrict__ out, int n) {
    __shared__ int buf[1024];
    __shared__ int carry;
    int t = threadIdx.x;
    if (t == 0) carry = 0;
    __syncthreads();
    int ntiles = (n + 1023) / 1024;
    for (int tile = 0; tile < ntiles; ++tile) {
        int idx = tile * 1024 + t;
        int v = (idx < n) ? in[idx] : 0;
        buf[t] = v;
        __syncthreads();
        for (int off = 1; off < 1024; off <<= 1) {
            int x = (t >= off) ? buf[t - off] : 0;
            __syncthreads();
            buf[t] += x;
            __syncthreads();
        }
        int incl = buf[t];
        int base = carry;
        if (idx < n) out[idx] = base + incl - v;
        __syncthreads();
        if (t == 0) carry = base + buf[1023];
        __syncthreads();
    }
    if (t == 0) out[n] = carry;
}

__global__ void dinv_kernel(const int* __restrict__ deg, float* __restrict__ dinv, int n) {
    int i = blockIdx.x * blockDim.x + threadIdx.x;
    if (i < n) dinv[i] = 1.0f / sqrtf((float)deg[i] + 1.0f);  // +1 = self loop
}

__global__ void csr_fill(const int* __restrict__ src, const int* __restrict__ dst,
                         const int* __restrict__ rowptr, int* __restrict__ fill,
                         int* __restrict__ col, int n) {
    int e = blockIdx.x * blockDim.x + threadIdx.x;
    if (e < n) {
        int d = dst[e];
        int pos = rowptr[d] + atomicAdd(&fill[d], 1);
        col[pos] = src[e];
    }
}

// ---------------- GEMM: Y[nrows,128] = X[nrows,128] @ W[128,128] ----------------
#define GBR 32
__global__ void gemm128(const float* __restrict__ X, const float* __restrict__ W,
                        float* __restrict__ Y, int nrows) {
    __shared__ float Xs[GBR][128];
    int t = threadIdx.x;         // 128 threads; t = output column
    int r0 = blockIdx.x * GBR;
    // load X tile (GBR rows x 128) as float4, coalesced
    const float4* xsrc = (const float4*)(X + (size_t)r0 * 128);
    float4* xdst = (float4*)(&Xs[0][0]);
    for (int i = t; i < GBR * 32; i += 128) {
        int r = i >> 5;
        if (r0 + r < nrows) xdst[i] = xsrc[i];
    }
    __syncthreads();
    float acc[GBR];
#pragma unroll
    for (int r = 0; r < GBR; ++r) acc[r] = 0.0f;
    for (int k0 = 0; k0 < 128; k0 += 4) {
        float w0 = W[(k0 + 0) * 128 + t];
        float w1 = W[(k0 + 1) * 128 + t];
        float w2 = W[(k0 + 2) * 128 + t];
        float w3 = W[(k0 + 3) * 128 + t];
#pragma unroll
        for (int r = 0; r < GBR; ++r) {
            float4 xv = *(const float4*)&Xs[r][k0];   // broadcast, conflict-free
            acc[r] = fmaf(xv.x, w0, acc[r]);
            acc[r] = fmaf(xv.y, w1, acc[r]);
            acc[r] = fmaf(xv.z, w2, acc[r]);
            acc[r] = fmaf(xv.w, w3, acc[r]);
        }
    }
#pragma unroll
    for (int r = 0; r < GBR; ++r)
        if (r0 + r < nrows) Y[(size_t)(r0 + r) * 128 + t] = acc[r];
}

// ---------------- aggregation: out[i] = dinv[i]*(sum_e dinv[src]*h[src]) + dinv[i]^2*h[i] + b
// optional BN(eval)+ReLU fused
__global__ void agg_kernel(const float* __restrict__ h, float* __restrict__ out,
                           const int* __restrict__ col, const int* __restrict__ rowptr,
                           const float* __restrict__ dinv, const float* __restrict__ bias,
                           const float* __restrict__ gamma, const float* __restrict__ beta,
                           int do_bn_relu) {
    int i = blockIdx.x;
    int t = threadIdx.x;  // 128 threads = feature dim
    int e0 = rowptr[i], e1 = rowptr[i + 1];
    float acc = 0.0f;
    for (int e = e0; e < e1; ++e) {
        int s = col[e];
        acc = fmaf(dinv[s], h[(size_t)s * 128 + t], acc);
    }
    float di = dinv[i];
    float v = di * acc + di * di * h[(size_t)i * 128 + t] + bias[t];
    if (do_bn_relu) {
        v = fmaf(v, gamma[t] * BN_RSQRT, beta[t]);
        v = v > 0.0f ? v : 0.0f;
    }
    out[(size_t)i * 128 + t] = v;
}

// ---------------- mean pool per graph (batch sorted -> contiguous ranges) ----------------
__global__ void pool_kernel(const float* __restrict__ h, const int* __restrict__ boffs,
                            float* __restrict__ gout) {
    int g = blockIdx.x;
    int t = threadIdx.x;  // 128
    int n0 = boffs[g], n1 = boffs[g + 1];
    float acc = 0.0f;
    for (int n = n0; n < n1; ++n) acc += h[(size_t)n * 128 + t];
    float cnt = (float)((n1 - n0) > 1 ? (n1 - n0) : 1);
    gout[(size_t)g * 128 + t] = acc / cnt;
}

// ---------------- classifier + log_softmax ----------------
__global__ void cls_kernel(const float* __restrict__ g, const float* __restrict__ W,
                           const float* __restrict__ b, float* __restrict__ out) {
    int i = blockIdx.x * blockDim.x + threadIdx.x;
    if (i >= N_GRAPHS) return;
    float z[N_CLASS];
#pragma unroll
    for (int c = 0; c < N_CLASS; ++c) z[c] = b[c];
    for (int k = 0; k < N_HID; ++k) {
        float gv = g[(size_t)i * N_HID + k];
#pragma unroll
        for (int c = 0; c < N_CLASS; ++c) z[c] = fmaf(gv, W[k * N_CLASS + c], z[c]);
    }
    float m = z[0];
#pragma unroll
    for (int c = 1; c < N_CLASS; ++c) m = fmaxf(m, z[c]);
    float s = 0.0f;
#pragma unroll
    for (int c = 0; c < N_CLASS; ++c) s += expf(z[c] - m);
    float l = logf(s);
#pragma unroll
    for (int c = 0; c < N_CLASS; ++c) out[(size_t)i * N_CLASS + c] = z[c] - m - l;
}

extern "C" void kernel_launch(void* const* d_in, const int* in_sizes, int n_in,
                              void* d_out, int out_size, void* d_ws, size_t ws_size,
                              hipStream_t stream) {
    const float* x     = (const float*)d_in[0];
    const int*   ei    = (const int*)d_in[1];
    const int*   batch = (const int*)d_in[2];
    const float* W1    = (const float*)d_in[3];
    const float* b1    = (const float*)d_in[4];
    const float* gamma = (const float*)d_in[5];
    const float* beta  = (const float*)d_in[6];
    const float* W2    = (const float*)d_in[7];
    const float* b2    = (const float*)d_in[8];
    const float* clsW  = (const float*)d_in[9];
    const float* clsb  = (const float*)d_in[10];

    const int N = in_sizes[0] / N_FEAT;   // 100000
    const int E = in_sizes[1] / 2;        // 1600000
    const int* src = ei;
    const int* dst = ei + E;

    // workspace carve (all 16B aligned)
    float* bufA = (float*)d_ws;                       // N*128 f32
    float* bufB = bufA + (size_t)N * 128;             // N*128 f32
    int*   col  = (int*)(bufB + (size_t)N * 128);     // E
    int*   rowptr = col + E;                          // N+1 (pad to N+4)
    int*   deg  = rowptr + (N + 4);                   // N
    int*   fill = deg + N;                            // N
    float* dinv = (float*)(fill + N);                 // N
    int*   bcnt = (int*)(dinv + N);                   // 512
    int*   boffs = bcnt + N_GRAPHS;                   // 513

    hipMemsetAsync(deg, 0, (size_t)N * 4, stream);
    hipMemsetAsync(fill, 0, (size_t)N * 4, stream);
    hipMemsetAsync(bcnt, 0, (size_t)N_GRAPHS * 4, stream);

    deg_kernel<<<(E + 255) / 256, 256, 0, stream>>>(dst, deg, E);
    bhist_kernel<<<(N + 255) / 256, 256, 0, stream>>>(batch, bcnt, N);
    scan_exclusive<<<1, 1024, 0, stream>>>(deg, rowptr, N);
    scan_exclusive<<<1, 1024, 0, stream>>>(bcnt, boffs, N_GRAPHS);
    dinv_kernel<<<(N + 255) / 256, 256, 0, stream>>>(deg, dinv, N);
    csr_fill<<<(E + 255) / 256, 256, 0, stream>>>(src, dst, rowptr, fill, col, E);

    // layer 1: h1 = x @ W1 ; agg + bias + BN + ReLU
    gemm128<<<(N + GBR - 1) / GBR, 128, 0, stream>>>(x, W1, bufA, N);
    agg_kernel<<<N, 128, 0, stream>>>(bufA, bufB, col, rowptr, dinv, b1, gamma, beta, 1);
    // layer 2: h2 = h1a @ W2 ; agg + bias
    gemm128<<<(N + GBR - 1) / GBR, 128, 0, stream>>>(bufB, W2, bufA, N);
    agg_kernel<<<N, 128, 0, stream>>>(bufA, bufB, col, rowptr, dinv, b2, gamma, beta, 0);

    float* out = (float*)d_out;
    float* gsec = out + (size_t)N_GRAPHS * N_CLASS;   // g occupies second slot of tuple
    pool_kernel<<<N_GRAPHS, 128, 0, stream>>>(bufB, boffs, gsec);
    cls_kernel<<<2, 256, 0, stream>>>(gsec, clsW, clsb, out);
}

// Round 2
// 653.581 us; speedup vs baseline: 1.7859x; 1.7859x over previous
//
#include <hip/hip_runtime.h>
#include <hip/hip_bf16.h>

#define N_NODES 100000
#define N_EDGES 1600000
#define N_FEAT 128
#define N_HID 128
#define N_CLASS 10
#define N_GRAPHS 512
// 1/sqrt(1 + 1e-5)
#define BN_RSQRT 0.9999950000374997f

typedef _Float16 half_t;
typedef __attribute__((ext_vector_type(2))) _Float16 half2v;
typedef __attribute__((ext_vector_type(4))) _Float16 half4v;
typedef __attribute__((ext_vector_type(8))) _Float16 half8v;
typedef __attribute__((ext_vector_type(4))) float floatx4;

// ---------------- degree / histogram ----------------
__global__ void deg_kernel(const int* __restrict__ dst, int* __restrict__ deg, int n) {
    int e = blockIdx.x * blockDim.x + threadIdx.x;
    if (e < n) atomicAdd(&deg[dst[e]], 1);
}

__global__ void bhist_kernel(const int* __restrict__ batch, int* __restrict__ cnt, int n) {
    int i = blockIdx.x * blockDim.x + threadIdx.x;
    if (i < n) atomicAdd(&cnt[batch[i]], 1);
}

// ---------------- multi-block exclusive scan (3 kernels) ----------------
__global__ void block_reduce(const int* __restrict__ in, int* __restrict__ bsums, int n) {
    __shared__ int s[256];
    int t = threadIdx.x;
    int i = blockIdx.x * 256 + t;
    s[t] = (i < n) ? in[i] : 0;
    __syncthreads();
    for (int off = 128; off > 0; off >>= 1) {
        if (t < off) s[t] += s[t + off];
        __syncthreads();
    }
    if (t == 0) bsums[blockIdx.x] = s[0];
}

// single block, 1024 threads, nb <= 1024: in-place exclusive scan of bsums
__global__ void scan_small(int* __restrict__ bsums, int nb) {
    __shared__ int buf[1024];
    int t = threadIdx.x;
    int v = (t < nb) ? bsums[t] : 0;
    buf[t] = v;
    __syncthreads();
    for (int off = 1; off < 1024; off <<= 1) {
        int x = (t >= off) ? buf[t - off] : 0;
        __syncthreads();
        buf[t] += x;
        __syncthreads();
    }
    if (t < nb) bsums[t] = buf[t] - v;
}

__global__ void scan_final(const int* __restrict__ in, const int* __restrict__ bsums,
                           int* __restrict__ out, int n, int total) {
    __shared__ int s[256];
    int t = threadIdx.x;
    int i = blockIdx.x * 256 + t;
    int v = (i < n) ? in[i] : 0;
    s[t] = v;
    __syncthreads();
    for (int off = 1; off < 256; off <<= 1) {
        int x = (t >= off) ? s[t - off] : 0;
        __syncthreads();
        s[t] += x;
        __syncthreads();
    }
    if (i < n) out[i] = bsums[blockIdx.x] + s[t] - v;
    if (i == 0) out[n] = total;
}

// 512-entry scan for graph offsets (one block, 512 threads)
__global__ void scan512(const int* __restrict__ in, int* __restrict__ out, int total) {
    __shared__ int buf[512];
    int t = threadIdx.x;
    int v = in[t];
    buf[t] = v;
    __syncthreads();
    for (int off = 1; off < 512; off <<= 1) {
        int x = (t >= off) ? buf[t - off] : 0;
        __syncthreads();
        buf[t] += x;
        __syncthreads();
    }
    out[t] = buf[t] - v;
    if (t == 511) out[512] = total;
}

__global__ void dinv_kernel(const int* __restrict__ deg, float* __restrict__ dinv, int n) {
    int i = blockIdx.x * blockDim.x + threadIdx.x;
    if (i < n) dinv[i] = rsqrtf((float)deg[i] + 1.0f);  // +1 = self loop
}

__global__ void csr_fill(const int* __restrict__ src, const int* __restrict__ dst,
                         const int* __restrict__ rowptr, int* __restrict__ fill,
                         int* __restrict__ col, int n) {
    int e = blockIdx.x * blockDim.x + threadIdx.x;
    if (e < n) {
        int d = dst[e];
        int pos = rowptr[d] + atomicAdd(&fill[d], 1);
        col[pos] = src[e];
    }
}

// ---------------- f32 -> f16 convert ----------------
__global__ void conv_f32_f16(const float* __restrict__ X, half_t* __restrict__ Xh, int n4) {
    int i = blockIdx.x * 256 + threadIdx.x;
    if (i < n4) {
        float4 v = ((const float4*)X)[i];
        half4v h = {(half_t)v.x, (half_t)v.y, (half_t)v.z, (half_t)v.w};
        ((half4v*)Xh)[i] = h;
    }
}

// ---------------- W[128x128] f32 -> Wt[128x128] f16 transposed ----------------
__global__ void prep_w(const float* __restrict__ W, half_t* __restrict__ Wt) {
    int i = blockIdx.x * 256 + threadIdx.x;  // 16384
    int c = i >> 7, k = i & 127;
    Wt[(size_t)c * 128 + k] = (half_t)W[(size_t)k * 128 + c];
}

// ---------------- MFMA GEMM: Y[nrows,128] = X[nrows,128] @ W, f16 in, f16 out ----
// Wt[c][k] = W[k][c]. Per wave: 16 rows x 128 cols, K=128.
__global__ __launch_bounds__(256) void gemm_mfma(
    const half_t* __restrict__ X, const half_t* __restrict__ Wt,
    half_t* __restrict__ Y, int nrows)
{
    int wave = threadIdx.x >> 6;
    int lane = threadIdx.x & 63;
    int n16  = lane & 15;
    int quad = lane >> 4;
    int r0 = blockIdx.x * 64 + wave * 16;
    if (r0 >= nrows) return;
    int row = r0 + n16;
    // A fragments: A[m=lane&15][k=quad*8+j], 4 K-chunks of 32
    const half8v* xrow = (const half8v*)(X + (size_t)row * 128);
    half8v a0 = xrow[0 * 4 + quad];
    half8v a1 = xrow[1 * 4 + quad];
    half8v a2 = xrow[2 * 4 + quad];
    half8v a3 = xrow[3 * 4 + quad];
#pragma unroll
    for (int c = 0; c < 8; ++c) {
        const half8v* wrow = (const half8v*)(Wt + (size_t)(c * 16 + n16) * 128);
        floatx4 acc = {0.f, 0.f, 0.f, 0.f};
        acc = __builtin_amdgcn_mfma_f32_16x16x32_f16(a0, wrow[0 * 4 + quad], acc, 0, 0, 0);
        acc = __builtin_amdgcn_mfma_f32_16x16x32_f16(a1, wrow[1 * 4 + quad], acc, 0, 0, 0);
        acc = __builtin_amdgcn_mfma_f32_16x16x32_f16(a2, wrow[2 * 4 + quad], acc, 0, 0, 0);
        acc = __builtin_amdgcn_mfma_f32_16x16x32_f16(a3, wrow[3 * 4 + quad], acc, 0, 0, 0);
        // D: col = lane&15, row = quad*4 + r
#pragma unroll
        for (int r = 0; r < 4; ++r)
            Y[(size_t)(r0 + quad * 4 + r) * 128 + c * 16 + n16] = (half_t)acc[r];
    }
}

// ---------------- aggregation (f16 h): one wave per node, 2 feats/lane ----------
__global__ __launch_bounds__(256) void agg_f16(
    const half_t* __restrict__ h, half_t* __restrict__ out,
    const int* __restrict__ col, const int* __restrict__ rowptr,
    const float* __restrict__ dinv, const float* __restrict__ bias,
    const float* __restrict__ gamma, const float* __restrict__ beta,
    int nnodes, int do_bn_relu)
{
    int wave = threadIdx.x >> 6;
    int lane = threadIdx.x & 63;
    int i = blockIdx.x * 4 + wave;
    if (i >= nnodes) return;
    int e0 = rowptr[i], e1 = rowptr[i + 1];
    float ax = 0.f, ay = 0.f;
    int e = e0;
    for (; e + 4 <= e1; e += 4) {
        int s0 = col[e], s1 = col[e + 1], s2 = col[e + 2], s3 = col[e + 3];
        half2v v0 = *(const half2v*)(h + (size_t)s0 * 128 + lane * 2);
        half2v v1 = *(const half2v*)(h + (size_t)s1 * 128 + lane * 2);
        half2v v2 = *(const half2v*)(h + (size_t)s2 * 128 + lane * 2);
        half2v v3 = *(const half2v*)(h + (size_t)s3 * 128 + lane * 2);
        float d0 = dinv[s0], d1 = dinv[s1], d2 = dinv[s2], d3 = dinv[s3];
        ax += d0 * (float)v0.x + d1 * (float)v1.x + d2 * (float)v2.x + d3 * (float)v3.x;
        ay += d0 * (float)v0.y + d1 * (float)v1.y + d2 * (float)v2.y + d3 * (float)v3.y;
    }
    for (; e < e1; ++e) {
        int s = col[e];
        half2v v = *(const half2v*)(h + (size_t)s * 128 + lane * 2);
        float d = dinv[s];
        ax += d * (float)v.x;
        ay += d * (float)v.y;
    }
    float di = dinv[i];
    half2v vs = *(const half2v*)(h + (size_t)i * 128 + lane * 2);
    float vx = di * ax + di * di * (float)vs.x + bias[lane * 2];
    float vy = di * ay + di * di * (float)vs.y + bias[lane * 2 + 1];
    if (do_bn_relu) {
        vx = fmaf(vx, gamma[lane * 2] * BN_RSQRT, beta[lane * 2]);
        vy = fmaf(vy, gamma[lane * 2 + 1] * BN_RSQRT, beta[lane * 2 + 1]);
        vx = vx > 0.f ? vx : 0.f;
        vy = vy > 0.f ? vy : 0.f;
    }
    half2v o = {(half_t)vx, (half_t)vy};
    *(half2v*)(out + (size_t)i * 128 + lane * 2) = o;
}

// ---------------- mean pool per graph (batch sorted) ----------------
__global__ void pool_f16(const half_t* __restrict__ h, const int* __restrict__ boffs,
                         float* __restrict__ gout) {
    int g = blockIdx.x;
    int t = threadIdx.x;  // 64 threads, 2 feats each
    int n0 = boffs[g], n1 = boffs[g + 1];
    float ax = 0.f, ay = 0.f;
    for (int n = n0; n < n1; ++n) {
        half2v v = *(const half2v*)(h + (size_t)n * 128 + t * 2);
        ax += (float)v.x;
        ay += (float)v.y;
    }
    float cnt = (float)((n1 - n0) > 1 ? (n1 - n0) : 1);
    gout[(size_t)g * 128 + t * 2] = ax / cnt;
    gout[(size_t)g * 128 + t * 2 + 1] = ay / cnt;
}

// ---------------- classifier + log_softmax ----------------
__global__ void cls_kernel(const float* __restrict__ g, const float* __restrict__ W,
                           const float* __restrict__ b, float* __restrict__ out) {
    int i = blockIdx.x * blockDim.x + threadIdx.x;
    if (i >= N_GRAPHS) return;
    float z[N_CLASS];
#pragma unroll
    for (int c = 0; c < N_CLASS; ++c) z[c] = b[c];
    for (int k = 0; k < N_HID; ++k) {
        float gv = g[(size_t)i * N_HID + k];
#pragma unroll
        for (int c = 0; c < N_CLASS; ++c) z[c] = fmaf(gv, W[k * N_CLASS + c], z[c]);
    }
    float m = z[0];
#pragma unroll
    for (int c = 1; c < N_CLASS; ++c) m = fmaxf(m, z[c]);
    float s = 0.f;
#pragma unroll
    for (int c = 0; c < N_CLASS; ++c) s += expf(z[c] - m);
    float l = logf(s);
#pragma unroll
    for (int c = 0; c < N_CLASS; ++c) out[(size_t)i * N_CLASS + c] = z[c] - m - l;
}

extern "C" void kernel_launch(void* const* d_in, const int* in_sizes, int n_in,
                              void* d_out, int out_size, void* d_ws, size_t ws_size,
                              hipStream_t stream) {
    const float* x     = (const float*)d_in[0];
    const int*   ei    = (const int*)d_in[1];
    const int*   batch = (const int*)d_in[2];
    const float* W1    = (const float*)d_in[3];
    const float* b1    = (const float*)d_in[4];
    const float* gamma = (const float*)d_in[5];
    const float* beta  = (const float*)d_in[6];
    const float* W2    = (const float*)d_in[7];
    const float* b2    = (const float*)d_in[8];
    const float* clsW  = (const float*)d_in[9];
    const float* clsb  = (const float*)d_in[10];

    const int N = in_sizes[0] / N_FEAT;   // 100000
    const int E = in_sizes[1] / 2;        // 1600000
    const int* src = ei;
    const int* dst = ei + E;

    // -------- workspace carve (16B aligned chunks) --------
    half_t* B0 = (half_t*)d_ws;                       // N*128 f16
    half_t* B1 = B0 + (size_t)N * 128;                // N*128 f16
    half_t* B2 = B1 + (size_t)N * 128;                // N*128 f16
    half_t* Wt1 = B2 + (size_t)N * 128;               // 16384 f16
    half_t* Wt2 = Wt1 + 16384;                        // 16384 f16
    int*   col    = (int*)(Wt2 + 16384);              // E
    int*   rowptr = col + E;                          // N+1 (+pad)
    int*   deg    = rowptr + (N + 4);                 // N
    int*   fill   = deg + N;                          // N
    float* dinv   = (float*)(fill + N);               // N
    int*   bcnt   = (int*)(dinv + N);                 // 512
    int*   boffs  = bcnt + N_GRAPHS;                  // 513 (+pad)
    int*   bsums  = boffs + N_GRAPHS + 4;             // ceil(N/256)=391 (+pad)

    hipMemsetAsync(deg, 0, (size_t)N * 4, stream);
    hipMemsetAsync(fill, 0, (size_t)N * 4, stream);
    hipMemsetAsync(bcnt, 0, (size_t)N_GRAPHS * 4, stream);

    const int nb = (N + 255) / 256;  // 391

    deg_kernel<<<(E + 255) / 256, 256, 0, stream>>>(dst, deg, E);
    bhist_kernel<<<(N + 255) / 256, 256, 0, stream>>>(batch, bcnt, N);
    // rowptr = exclusive_scan(deg), rowptr[N] = E
    block_reduce<<<nb, 256, 0, stream>>>(deg, bsums, N);
    scan_small<<<1, 1024, 0, stream>>>(bsums, nb);
    scan_final<<<nb, 256, 0, stream>>>(deg, bsums, rowptr, N, E);
    // boffs = exclusive_scan(bcnt), boffs[512] = N
    scan512<<<1, 512, 0, stream>>>(bcnt, boffs, N);
    dinv_kernel<<<(N + 255) / 256, 256, 0, stream>>>(deg, dinv, N);
    csr_fill<<<(E + 255) / 256, 256, 0, stream>>>(src, dst, rowptr, fill, col, E);

    // weights -> f16 transposed; x -> f16
    prep_w<<<64, 256, 0, stream>>>(W1, Wt1);
    prep_w<<<64, 256, 0, stream>>>(W2, Wt2);
    conv_f32_f16<<<((N * 32) + 255) / 256, 256, 0, stream>>>(x, B0, N * 32);

    // layer 1
    gemm_mfma<<<(N + 63) / 64, 256, 0, stream>>>(B0, Wt1, B1, N);
    agg_f16<<<(N + 3) / 4, 256, 0, stream>>>(B1, B2, col, rowptr, dinv, b1, gamma, beta, N, 1);
    // layer 2
    gemm_mfma<<<(N + 63) / 64, 256, 0, stream>>>(B2, Wt2, B0, N);
    agg_f16<<<(N + 3) / 4, 256, 0, stream>>>(B0, B1, col, rowptr, dinv, b2, gamma, beta, N, 0);

    float* out = (float*)d_out;
    float* gsec = out + (size_t)N_GRAPHS * N_CLASS;
    pool_f16<<<N_GRAPHS, 64, 0, stream>>>(B1, boffs, gsec);
    cls_kernel<<<2, 256, 0, stream>>>(gsec, clsW, clsb, out);
}

// Round 3
// 548.309 us; speedup vs baseline: 2.1288x; 1.1920x over previous
//
#include <hip/hip_runtime.h>
#include <hip/hip_bf16.h>

#define N_NODES 100000
#define N_EDGES 1600000
#define N_FEAT 128
#define N_HID 128
#define N_CLASS 10
#define N_GRAPHS 512
// 1/sqrt(1 + 1e-5)
#define BN_RSQRT 0.9999950000374997f

typedef _Float16 half_t;
typedef __attribute__((ext_vector_type(2))) _Float16 half2v;
typedef __attribute__((ext_vector_type(8))) _Float16 half8v;
typedef __attribute__((ext_vector_type(4))) float floatx4;

// ---------------- degree ----------------
__global__ void deg_kernel(const int* __restrict__ dst, int* __restrict__ deg, int n) {
    int e = blockIdx.x * blockDim.x + threadIdx.x;
    if (e < n) atomicAdd(&deg[dst[e]], 1);
}

// ---------------- multi-block exclusive scan (3 kernels) ----------------
__global__ void block_reduce(const int* __restrict__ in, int* __restrict__ bsums, int n) {
    __shared__ int s[256];
    int t = threadIdx.x;
    int i = blockIdx.x * 256 + t;
    s[t] = (i < n) ? in[i] : 0;
    __syncthreads();
    for (int off = 128; off > 0; off >>= 1) {
        if (t < off) s[t] += s[t + off];
        __syncthreads();
    }
    if (t == 0) bsums[blockIdx.x] = s[0];
}

__global__ void scan_small(int* __restrict__ bsums, int nb) {
    __shared__ int buf[1024];
    int t = threadIdx.x;
    int v = (t < nb) ? bsums[t] : 0;
    buf[t] = v;
    __syncthreads();
    for (int off = 1; off < 1024; off <<= 1) {
        int x = (t >= off) ? buf[t - off] : 0;
        __syncthreads();
        buf[t] += x;
        __syncthreads();
    }
    if (t < nb) bsums[t] = buf[t] - v;
}

__global__ void scan_final(const int* __restrict__ in, const int* __restrict__ bsums,
                           int* __restrict__ out, int n, int total) {
    __shared__ int s[256];
    int t = threadIdx.x;
    int i = blockIdx.x * 256 + t;
    int v = (i < n) ? in[i] : 0;
    s[t] = v;
    __syncthreads();
    for (int off = 1; off < 256; off <<= 1) {
        int x = (t >= off) ? s[t - off] : 0;
        __syncthreads();
        s[t] += x;
        __syncthreads();
    }
    if (i < n) out[i] = bsums[blockIdx.x] + s[t] - v;
    if (i == 0) out[n] = total;
}

// ---------------- graph offsets from sorted batch (boundary detect) ----------------
__global__ void boffs_kernel(const int* __restrict__ batch, int* __restrict__ boffs, int n) {
    int i = blockIdx.x * 256 + threadIdx.x;
    if (i >= n) return;
    int b = batch[i];
    int prev = (i == 0) ? -1 : batch[i - 1];
    for (int g = prev + 1; g <= b; ++g) boffs[g] = i;
    if (i == n - 1)
        for (int g = b + 1; g <= N_GRAPHS; ++g) boffs[g] = n;
}

__global__ void dinv_kernel(const int* __restrict__ deg, float* __restrict__ dinv, int n) {
    int i = blockIdx.x * blockDim.x + threadIdx.x;
    if (i < n) dinv[i] = rsqrtf((float)deg[i] + 1.0f);  // +1 = self loop
}

// ---------------- CSR fill, XCD-partitioned by dst range ----------------
// blockIdx%8 ~ XCD (round-robin dispatch). Each dst-range's col/fillptr lines are
// touched by one XCD only -> no cross-XCD partial-line write-back amplification.
#define CSR_CHUNK 4096
__global__ __launch_bounds__(256) void csr_fill_xcd(
    const int* __restrict__ src, const int* __restrict__ dst,
    int* __restrict__ fillptr, int* __restrict__ col, int nchunks, int E)
{
    int r = blockIdx.x & 7;
    int chunk = blockIdx.x >> 3;
    if (chunk >= nchunks) return;
    int base = chunk * CSR_CHUNK;
#pragma unroll 4
    for (int k = 0; k < CSR_CHUNK / 256; ++k) {
        int e = base + k * 256 + threadIdx.x;
        if (e < E) {
            int d = dst[e];
            int rr = (d * 8) / N_NODES;  // compile-time magic-mul division
            if (rr == r) {
                int pos = atomicAdd(&fillptr[d], 1);
                col[pos] = src[e];
            }
        }
    }
}

// ---------------- W[128x128] f32 -> Wt[128x128] f16 transposed ----------------
__global__ void prep_w(const float* __restrict__ W, half_t* __restrict__ Wt) {
    int i = blockIdx.x * 256 + threadIdx.x;  // 16384
    int c = i >> 7, k = i & 127;
    Wt[(size_t)c * 128 + k] = (half_t)W[(size_t)k * 128 + c];
}

// ---------------- MFMA GEMM (f32 input): Y = dinv[row] * (X @ W), f16 out ------
__global__ __launch_bounds__(256) void gemm1_mfma(
    const float* __restrict__ X, const half_t* __restrict__ Wt,
    const float* __restrict__ dinv, half_t* __restrict__ Y, int nrows)
{
    int wave = threadIdx.x >> 6;
    int lane = threadIdx.x & 63;
    int n16  = lane & 15;
    int quad = lane >> 4;
    int r0 = blockIdx.x * 64 + wave * 16;
    if (r0 >= nrows) return;
    int row = r0 + n16;
    const float4* xrow = (const float4*)(X + (size_t)row * 128);
    half8v a[4];
#pragma unroll
    for (int kc = 0; kc < 4; ++kc) {
        float4 f0 = xrow[kc * 8 + quad * 2];
        float4 f1 = xrow[kc * 8 + quad * 2 + 1];
        half8v t = {(half_t)f0.x, (half_t)f0.y, (half_t)f0.z, (half_t)f0.w,
                    (half_t)f1.x, (half_t)f1.y, (half_t)f1.z, (half_t)f1.w};
        a[kc] = t;
    }
    float dr[4];
#pragma unroll
    for (int r = 0; r < 4; ++r) dr[r] = dinv[r0 + quad * 4 + r];
#pragma unroll
    for (int c = 0; c < 8; ++c) {
        const half8v* wrow = (const half8v*)(Wt + (size_t)(c * 16 + n16) * 128);
        floatx4 acc = {0.f, 0.f, 0.f, 0.f};
        acc = __builtin_amdgcn_mfma_f32_16x16x32_f16(a[0], wrow[0 * 4 + quad], acc, 0, 0, 0);
        acc = __builtin_amdgcn_mfma_f32_16x16x32_f16(a[1], wrow[1 * 4 + quad], acc, 0, 0, 0);
        acc = __builtin_amdgcn_mfma_f32_16x16x32_f16(a[2], wrow[2 * 4 + quad], acc, 0, 0, 0);
        acc = __builtin_amdgcn_mfma_f32_16x16x32_f16(a[3], wrow[3 * 4 + quad], acc, 0, 0, 0);
#pragma unroll
        for (int r = 0; r < 4; ++r)
            Y[(size_t)(r0 + quad * 4 + r) * 128 + c * 16 + n16] = (half_t)(acc[r] * dr[r]);
    }
}

// ---------------- MFMA GEMM (f16 input): Y = dinv[row] * (X @ W), f16 out ------
__global__ __launch_bounds__(256) void gemm2_mfma(
    const half_t* __restrict__ X, const half_t* __restrict__ Wt,
    const float* __restrict__ dinv, half_t* __restrict__ Y, int nrows)
{
    int wave = threadIdx.x >> 6;
    int lane = threadIdx.x & 63;
    int n16  = lane & 15;
    int quad = lane >> 4;
    int r0 = blockIdx.x * 64 + wave * 16;
    if (r0 >= nrows) return;
    int row = r0 + n16;
    const half8v* xrow = (const half8v*)(X + (size_t)row * 128);
    half8v a0 = xrow[0 * 4 + quad];
    half8v a1 = xrow[1 * 4 + quad];
    half8v a2 = xrow[2 * 4 + quad];
    half8v a3 = xrow[3 * 4 + quad];
    float dr[4];
#pragma unroll
    for (int r = 0; r < 4; ++r) dr[r] = dinv[r0 + quad * 4 + r];
#pragma unroll
    for (int c = 0; c < 8; ++c) {
        const half8v* wrow = (const half8v*)(Wt + (size_t)(c * 16 + n16) * 128);
        floatx4 acc = {0.f, 0.f, 0.f, 0.f};
        acc = __builtin_amdgcn_mfma_f32_16x16x32_f16(a0, wrow[0 * 4 + quad], acc, 0, 0, 0);
        acc = __builtin_amdgcn_mfma_f32_16x16x32_f16(a1, wrow[1 * 4 + quad], acc, 0, 0, 0);
        acc = __builtin_amdgcn_mfma_f32_16x16x32_f16(a2, wrow[2 * 4 + quad], acc, 0, 0, 0);
        acc = __builtin_amdgcn_mfma_f32_16x16x32_f16(a3, wrow[3 * 4 + quad], acc, 0, 0, 0);
#pragma unroll
        for (int r = 0; r < 4; ++r)
            Y[(size_t)(r0 + quad * 4 + r) * 128 + c * 16 + n16] = (half_t)(acc[r] * dr[r]);
    }
}

// ---------------- aggregation over pre-scaled hs = dinv*h ----------------------
// out[i] = dinv[i]*(sum_e hs[col[e]] + hs[i]) + bias  (+ optional BN/ReLU)
__global__ __launch_bounds__(256) void agg_f16(
    const half_t* __restrict__ hs, half_t* __restrict__ out,
    const int* __restrict__ col, const int* __restrict__ rowptr,
    const float* __restrict__ dinv, const float* __restrict__ bias,
    const float* __restrict__ gamma, const float* __restrict__ beta,
    int nnodes, int do_bn_relu)
{
    int wave = threadIdx.x >> 6;
    int lane = threadIdx.x & 63;
    int i = blockIdx.x * 4 + wave;
    if (i >= nnodes) return;
    int e0 = rowptr[i], e1 = rowptr[i + 1];
    float ax = 0.f, ay = 0.f;
    int e = e0;
    for (; e + 8 <= e1; e += 8) {
        int s0 = col[e], s1 = col[e + 1], s2 = col[e + 2], s3 = col[e + 3];
        int s4 = col[e + 4], s5 = col[e + 5], s6 = col[e + 6], s7 = col[e + 7];
        half2v v0 = *(const half2v*)(hs + (size_t)s0 * 128 + lane * 2);
        half2v v1 = *(const half2v*)(hs + (size_t)s1 * 128 + lane * 2);
        half2v v2 = *(const half2v*)(hs + (size_t)s2 * 128 + lane * 2);
        half2v v3 = *(const half2v*)(hs + (size_t)s3 * 128 + lane * 2);
        half2v v4 = *(const half2v*)(hs + (size_t)s4 * 128 + lane * 2);
        half2v v5 = *(const half2v*)(hs + (size_t)s5 * 128 + lane * 2);
        half2v v6 = *(const half2v*)(hs + (size_t)s6 * 128 + lane * 2);
        half2v v7 = *(const half2v*)(hs + (size_t)s7 * 128 + lane * 2);
        ax += (float)v0.x + (float)v1.x + (float)v2.x + (float)v3.x
            + (float)v4.x + (float)v5.x + (float)v6.x + (float)v7.x;
        ay += (float)v0.y + (float)v1.y + (float)v2.y + (float)v3.y
            + (float)v4.y + (float)v5.y + (float)v6.y + (float)v7.y;
    }
    for (; e < e1; ++e) {
        int s = col[e];
        half2v v = *(const half2v*)(hs + (size_t)s * 128 + lane * 2);
        ax += (float)v.x;
        ay += (float)v.y;
    }
    float di = dinv[i];
    half2v vs = *(const half2v*)(hs + (size_t)i * 128 + lane * 2);
    float vx = di * (ax + (float)vs.x) + bias[lane * 2];
    float vy = di * (ay + (float)vs.y) + bias[lane * 2 + 1];
    if (do_bn_relu) {
        vx = fmaf(vx, gamma[lane * 2] * BN_RSQRT, beta[lane * 2]);
        vy = fmaf(vy, gamma[lane * 2 + 1] * BN_RSQRT, beta[lane * 2 + 1]);
        vx = vx > 0.f ? vx : 0.f;
        vy = vy > 0.f ? vy : 0.f;
    }
    half2v o = {(half_t)vx, (half_t)vy};
    *(half2v*)(out + (size_t)i * 128 + lane * 2) = o;
}

// ---------------- mean pool per graph (batch sorted) ----------------
__global__ void pool_f16(const half_t* __restrict__ h, const int* __restrict__ boffs,
                         float* __restrict__ gout) {
    int g = blockIdx.x;
    int t = threadIdx.x;  // 64 threads, 2 feats each
    int n0 = boffs[g], n1 = boffs[g + 1];
    float ax = 0.f, ay = 0.f;
    for (int n = n0; n < n1; ++n) {
        half2v v = *(const half2v*)(h + (size_t)n * 128 + t * 2);
        ax += (float)v.x;
        ay += (float)v.y;
    }
    float cnt = (float)((n1 - n0) > 1 ? (n1 - n0) : 1);
    gout[(size_t)g * 128 + t * 2] = ax / cnt;
    gout[(size_t)g * 128 + t * 2 + 1] = ay / cnt;
}

// ---------------- classifier + log_softmax ----------------
__global__ void cls_kernel(const float* __restrict__ g, const float* __restrict__ W,
                           const float* __restrict__ b, float* __restrict__ out) {
    int i = blockIdx.x * blockDim.x + threadIdx.x;
    if (i >= N_GRAPHS) return;
    float z[N_CLASS];
#pragma unroll
    for (int c = 0; c < N_CLASS; ++c) z[c] = b[c];
    for (int k = 0; k < N_HID; ++k) {
        float gv = g[(size_t)i * N_HID + k];
#pragma unroll
        for (int c = 0; c < N_CLASS; ++c) z[c] = fmaf(gv, W[k * N_CLASS + c], z[c]);
    }
    float m = z[0];
#pragma unroll
    for (int c = 1; c < N_CLASS; ++c) m = fmaxf(m, z[c]);
    float s = 0.f;
#pragma unroll
    for (int c = 0; c < N_CLASS; ++c) s += expf(z[c] - m);
    float l = logf(s);
#pragma unroll
    for (int c = 0; c < N_CLASS; ++c) out[(size_t)i * N_CLASS + c] = z[c] - m - l;
}

extern "C" void kernel_launch(void* const* d_in, const int* in_sizes, int n_in,
                              void* d_out, int out_size, void* d_ws, size_t ws_size,
                              hipStream_t stream) {
    const float* x     = (const float*)d_in[0];
    const int*   ei    = (const int*)d_in[1];
    const int*   batch = (const int*)d_in[2];
    const float* W1    = (const float*)d_in[3];
    const float* b1    = (const float*)d_in[4];
    const float* gamma = (const float*)d_in[5];
    const float* beta  = (const float*)d_in[6];
    const float* W2    = (const float*)d_in[7];
    const float* b2    = (const float*)d_in[8];
    const float* clsW  = (const float*)d_in[9];
    const float* clsb  = (const float*)d_in[10];

    const int N = in_sizes[0] / N_FEAT;   // 100000
    const int E = in_sizes[1] / 2;        // 1600000
    const int* src = ei;
    const int* dst = ei + E;

    // -------- workspace carve --------
    half_t* BA = (half_t*)d_ws;                       // N*128 f16
    half_t* BB = BA + (size_t)N * 128;                // N*128 f16
    half_t* Wt1 = BB + (size_t)N * 128;               // 16384 f16
    half_t* Wt2 = Wt1 + 16384;                        // 16384 f16
    int*   col     = (int*)(Wt2 + 16384);             // E
    int*   rowptr  = col + E;                         // N+1 (+pad)
    int*   deg     = rowptr + (N + 4);                // N
    int*   fillptr = deg + N;                         // N
    float* dinv    = (float*)(fillptr + N);           // N
    int*   boffs   = (int*)(dinv + N);                // 513 (+pad)
    int*   bsums   = boffs + N_GRAPHS + 4;            // ceil(N/256)=391 (+pad)

    hipMemsetAsync(deg, 0, (size_t)N * 4, stream);

    const int nb = (N + 255) / 256;  // 391
    const int nchunks = (E + CSR_CHUNK - 1) / CSR_CHUNK;  // 391

    deg_kernel<<<(E + 255) / 256, 256, 0, stream>>>(dst, deg, E);
    boffs_kernel<<<nb, 256, 0, stream>>>(batch, boffs, N);
    // rowptr = exclusive_scan(deg), rowptr[N] = E
    block_reduce<<<nb, 256, 0, stream>>>(deg, bsums, N);
    scan_small<<<1, 1024, 0, stream>>>(bsums, nb);
    scan_final<<<nb, 256, 0, stream>>>(deg, bsums, rowptr, N, E);
    dinv_kernel<<<(N + 255) / 256, 256, 0, stream>>>(deg, dinv, N);
    // fillptr <- rowptr, then XCD-partitioned fill
    hipMemcpyAsync(fillptr, rowptr, (size_t)N * 4, hipMemcpyDeviceToDevice, stream);
    csr_fill_xcd<<<nchunks * 8, 256, 0, stream>>>(src, dst, fillptr, col, nchunks, E);

    prep_w<<<64, 256, 0, stream>>>(W1, Wt1);
    prep_w<<<64, 256, 0, stream>>>(W2, Wt2);

    // layer 1: BA = dinv*(x@W1); BB = agg(BA)+b1, BN, ReLU
    gemm1_mfma<<<(N + 63) / 64, 256, 0, stream>>>(x, Wt1, dinv, BA, N);
    agg_f16<<<(N + 3) / 4, 256, 0, stream>>>(BA, BB, col, rowptr, dinv, b1, gamma, beta, N, 1);
    // layer 2: BA = dinv*(BB@W2); BB = agg(BA)+b2
    gemm2_mfma<<<(N + 63) / 64, 256, 0, stream>>>(BB, Wt2, dinv, BA, N);
    agg_f16<<<(N + 3) / 4, 256, 0, stream>>>(BA, BB, col, rowptr, dinv, b2, gamma, beta, N, 0);

    float* out = (float*)d_out;
    float* gsec = out + (size_t)N_GRAPHS * N_CLASS;
    pool_f16<<<N_GRAPHS, 64, 0, stream>>>(BB, boffs, gsec);
    cls_kernel<<<2, 256, 0, stream>>>(gsec, clsW, clsb, out);
}

// Round 4
// 531.544 us; speedup vs baseline: 2.1960x; 1.0315x over previous
//
#include <hip/hip_runtime.h>
#include <hip/hip_bf16.h>

#define N_NODES 100000
#define N_EDGES 1600000
#define N_FEAT 128
#define N_HID 128
#define N_CLASS 10
#define N_GRAPHS 512
// 1/sqrt(1 + 1e-5)
#define BN_RSQRT 0.9999950000374997f

typedef _Float16 half_t;
typedef __attribute__((ext_vector_type(2))) _Float16 half2v;
typedef __attribute__((ext_vector_type(4))) _Float16 half4v;
typedef __attribute__((ext_vector_type(8))) _Float16 half8v;
typedef __attribute__((ext_vector_type(4))) float floatx4;

#if defined(__has_builtin)
#if __has_builtin(__builtin_amdgcn_fdot2)
#define HAVE_FDOT2 1
#endif
#endif
#ifdef HAVE_FDOT2
#define FDOT2(a, b, c) __builtin_amdgcn_fdot2((a), (b), (c), false)
#else
#define FDOT2(a, b, c) ((c) + (float)(a).x * (float)(b).x + (float)(a).y * (float)(b).y)
#endif

// ---------------- degree, XCD-partitioned by dst range ----------------
#define CSR_CHUNK 4096
__global__ __launch_bounds__(256) void deg_xcd(
    const int* __restrict__ dst, int* __restrict__ deg, int nchunks, int E)
{
    int r = blockIdx.x & 7;
    int chunk = blockIdx.x >> 3;
    if (chunk >= nchunks) return;
    int base = chunk * CSR_CHUNK;
#pragma unroll 4
    for (int k = 0; k < CSR_CHUNK / 256; ++k) {
        int e = base + k * 256 + threadIdx.x;
        if (e < E) {
            int d = dst[e];
            int rr = (d * 8) / N_NODES;
            if (rr == r) atomicAdd(&deg[d], 1);
        }
    }
}

// ---------------- multi-block exclusive scan ----------------
__global__ void block_reduce(const int* __restrict__ in, int* __restrict__ bsums, int n) {
    __shared__ int s[256];
    int t = threadIdx.x;
    int i = blockIdx.x * 256 + t;
    s[t] = (i < n) ? in[i] : 0;
    __syncthreads();
    for (int off = 128; off > 0; off >>= 1) {
        if (t < off) s[t] += s[t + off];
        __syncthreads();
    }
    if (t == 0) bsums[blockIdx.x] = s[0];
}

__global__ void scan_small(int* __restrict__ bsums, int nb) {
    __shared__ int buf[1024];
    int t = threadIdx.x;
    int v = (t < nb) ? bsums[t] : 0;
    buf[t] = v;
    __syncthreads();
    for (int off = 1; off < 1024; off <<= 1) {
        int x = (t >= off) ? buf[t - off] : 0;
        __syncthreads();
        buf[t] += x;
        __syncthreads();
    }
    if (t < nb) bsums[t] = buf[t] - v;
}

// writes rowptr[i], fillptr[i] (= rowptr[i]), dinv[i], rowptr[N]=E
__global__ void scan_final(const int* __restrict__ in, const int* __restrict__ bsums,
                           int* __restrict__ rowptr, int* __restrict__ fillptr,
                           float* __restrict__ dinv, int n, int total) {
    __shared__ int s[256];
    int t = threadIdx.x;
    int i = blockIdx.x * 256 + t;
    int v = (i < n) ? in[i] : 0;
    s[t] = v;
    __syncthreads();
    for (int off = 1; off < 256; off <<= 1) {
        int x = (t >= off) ? s[t - off] : 0;
        __syncthreads();
        s[t] += x;
        __syncthreads();
    }
    if (i < n) {
        int excl = bsums[blockIdx.x] + s[t] - v;
        rowptr[i] = excl;
        fillptr[i] = excl;
        dinv[i] = rsqrtf((float)v + 1.0f);  // +1 = self loop
    }
    if (i == 0) rowptr[n] = total;
}

// ---------------- graph offsets from sorted batch (boundary detect) --------------
__global__ void boffs_kernel(const int* __restrict__ batch, int* __restrict__ boffs, int n) {
    int i = blockIdx.x * 256 + threadIdx.x;
    if (i >= n) return;
    int b = batch[i];
    int prev = (i == 0) ? -1 : batch[i - 1];
    for (int g = prev + 1; g <= b; ++g) boffs[g] = i;
    if (i == n - 1)
        for (int g = b + 1; g <= N_GRAPHS; ++g) boffs[g] = n;
}

// ---------------- CSR fill, XCD-partitioned by dst range ----------------
__global__ __launch_bounds__(256) void csr_fill_xcd(
    const int* __restrict__ src, const int* __restrict__ dst,
    int* __restrict__ fillptr, int* __restrict__ col, int nchunks, int E)
{
    int r = blockIdx.x & 7;
    int chunk = blockIdx.x >> 3;
    if (chunk >= nchunks) return;
    int base = chunk * CSR_CHUNK;
#pragma unroll 4
    for (int k = 0; k < CSR_CHUNK / 256; ++k) {
        int e = base + k * 256 + threadIdx.x;
        if (e < E) {
            int d = dst[e];
            int rr = (d * 8) / N_NODES;
            if (rr == r) {
                int pos = atomicAdd(&fillptr[d], 1);
                col[pos] = src[e];
            }
        }
    }
}

// ---------------- both W[128x128] f32 -> Wt f16 transposed, one launch ----------
__global__ void prep_w(const float* __restrict__ W1, half_t* __restrict__ Wt1,
                       const float* __restrict__ W2, half_t* __restrict__ Wt2) {
    int i = blockIdx.x * 256 + threadIdx.x;  // 0..32767
    const float* W = (i < 16384) ? W1 : W2;
    half_t* Wt = (i < 16384) ? Wt1 : Wt2;
    int j = i & 16383;
    int c = j >> 7, k = j & 127;
    Wt[(size_t)c * 128 + k] = (half_t)W[(size_t)k * 128 + c];
}

// ---------------- MFMA GEMM (f32 input): Y = dinv[row]*(X@W), f16 out -----------
// D transposed via operand swap: lane n16 = node row, (quad,reg) = out col.
__global__ __launch_bounds__(256) void gemm1_mfma(
    const float* __restrict__ X, const half_t* __restrict__ Wt,
    const float* __restrict__ dinv, half_t* __restrict__ Y, int nrows)
{
    int wave = threadIdx.x >> 6;
    int lane = threadIdx.x & 63;
    int n16  = lane & 15;
    int quad = lane >> 4;
    int r0 = blockIdx.x * 64 + wave * 16;
    if (r0 >= nrows) return;
    int row = r0 + n16;
    const float4* xrow = (const float4*)(X + (size_t)row * 128);
    half8v a[4];
#pragma unroll
    for (int kc = 0; kc < 4; ++kc) {
        float4 f0 = xrow[kc * 8 + quad * 2];
        float4 f1 = xrow[kc * 8 + quad * 2 + 1];
        half8v t = {(half_t)f0.x, (half_t)f0.y, (half_t)f0.z, (half_t)f0.w,
                    (half_t)f1.x, (half_t)f1.y, (half_t)f1.z, (half_t)f1.w};
        a[kc] = t;
    }
    float dr = dinv[row];
#pragma unroll
    for (int c = 0; c < 8; ++c) {
        const half8v* wrow = (const half8v*)(Wt + (size_t)(c * 16 + n16) * 128);
        floatx4 acc = {0.f, 0.f, 0.f, 0.f};
        acc = __builtin_amdgcn_mfma_f32_16x16x32_f16(wrow[0 * 4 + quad], a[0], acc, 0, 0, 0);
        acc = __builtin_amdgcn_mfma_f32_16x16x32_f16(wrow[1 * 4 + quad], a[1], acc, 0, 0, 0);
        acc = __builtin_amdgcn_mfma_f32_16x16x32_f16(wrow[2 * 4 + quad], a[2], acc, 0, 0, 0);
        acc = __builtin_amdgcn_mfma_f32_16x16x32_f16(wrow[3 * 4 + quad], a[3], acc, 0, 0, 0);
        half4v o = {(half_t)(acc[0] * dr), (half_t)(acc[1] * dr),
                    (half_t)(acc[2] * dr), (half_t)(acc[3] * dr)};
        *(half4v*)(Y + (size_t)row * 128 + c * 16 + quad * 4) = o;
    }
}

// ---------------- MFMA GEMM (f16 input): Y = dinv[row]*(X@W), f16 out -----------
__global__ __launch_bounds__(256) void gemm2_mfma(
    const half_t* __restrict__ X, const half_t* __restrict__ Wt,
    const float* __restrict__ dinv, half_t* __restrict__ Y, int nrows)
{
    int wave = threadIdx.x >> 6;
    int lane = threadIdx.x & 63;
    int n16  = lane & 15;
    int quad = lane >> 4;
    int r0 = blockIdx.x * 64 + wave * 16;
    if (r0 >= nrows) return;
    int row = r0 + n16;
    const half8v* xrow = (const half8v*)(X + (size_t)row * 128);
    half8v a0 = xrow[0 * 4 + quad];
    half8v a1 = xrow[1 * 4 + quad];
    half8v a2 = xrow[2 * 4 + quad];
    half8v a3 = xrow[3 * 4 + quad];
    float dr = dinv[row];
#pragma unroll
    for (int c = 0; c < 8; ++c) {
        const half8v* wrow = (const half8v*)(Wt + (size_t)(c * 16 + n16) * 128);
        floatx4 acc = {0.f, 0.f, 0.f, 0.f};
        acc = __builtin_amdgcn_mfma_f32_16x16x32_f16(wrow[0 * 4 + quad], a0, acc, 0, 0, 0);
        acc = __builtin_amdgcn_mfma_f32_16x16x32_f16(wrow[1 * 4 + quad], a1, acc, 0, 0, 0);
        acc = __builtin_amdgcn_mfma_f32_16x16x32_f16(wrow[2 * 4 + quad], a2, acc, 0, 0, 0);
        acc = __builtin_amdgcn_mfma_f32_16x16x32_f16(wrow[3 * 4 + quad], a3, acc, 0, 0, 0);
        half4v o = {(half_t)(acc[0] * dr), (half_t)(acc[1] * dr),
                    (half_t)(acc[2] * dr), (half_t)(acc[3] * dr)};
        *(half4v*)(Y + (size_t)row * 128 + c * 16 + quad * 4) = o;
    }
}

// ---------------- aggregation over pre-scaled hs = dinv*h ----------------------
// out[i] = dinv[i]*(sum_e hs[col[e]] + hs[i]) + bias  (+ optional BN/ReLU)
__global__ __launch_bounds__(256) void agg_f16(
    const half_t* __restrict__ hs, half_t* __restrict__ out,
    const int* __restrict__ col, const int* __restrict__ rowptr,
    const float* __restrict__ dinv, const float* __restrict__ bias,
    const float* __restrict__ gamma, const float* __restrict__ beta,
    int nnodes, int do_bn_relu)
{
    int wave = threadIdx.x >> 6;
    int lane = threadIdx.x & 63;
    int i = blockIdx.x * 4 + wave;
    if (i >= nnodes) return;
    int e0 = rowptr[i], e1 = rowptr[i + 1];
    const char* hb = (const char*)hs;
    unsigned lo = (unsigned)lane << 2;
    const half2v bx = {(half_t)1.0f, (half_t)0.0f};
    const half2v by = {(half_t)0.0f, (half_t)1.0f};
    float ax0 = 0.f, ay0 = 0.f, ax1 = 0.f, ay1 = 0.f;
    int e = e0;
    for (; e + 8 <= e1; e += 8) {
        half2v v0 = *(const half2v*)(hb + (((unsigned)col[e + 0] << 8) | lo));
        half2v v1 = *(const half2v*)(hb + (((unsigned)col[e + 1] << 8) | lo));
        half2v v2 = *(const half2v*)(hb + (((unsigned)col[e + 2] << 8) | lo));
        half2v v3 = *(const half2v*)(hb + (((unsigned)col[e + 3] << 8) | lo));
        half2v v4 = *(const half2v*)(hb + (((unsigned)col[e + 4] << 8) | lo));
        half2v v5 = *(const half2v*)(hb + (((unsigned)col[e + 5] << 8) | lo));
        half2v v6 = *(const half2v*)(hb + (((unsigned)col[e + 6] << 8) | lo));
        half2v v7 = *(const half2v*)(hb + (((unsigned)col[e + 7] << 8) | lo));
        ax0 = FDOT2(v0, bx, ax0); ay0 = FDOT2(v0, by, ay0);
        ax1 = FDOT2(v1, bx, ax1); ay1 = FDOT2(v1, by, ay1);
        ax0 = FDOT2(v2, bx, ax0); ay0 = FDOT2(v2, by, ay0);
        ax1 = FDOT2(v3, bx, ax1); ay1 = FDOT2(v3, by, ay1);
        ax0 = FDOT2(v4, bx, ax0); ay0 = FDOT2(v4, by, ay0);
        ax1 = FDOT2(v5, bx, ax1); ay1 = FDOT2(v5, by, ay1);
        ax0 = FDOT2(v6, bx, ax0); ay0 = FDOT2(v6, by, ay0);
        ax1 = FDOT2(v7, bx, ax1); ay1 = FDOT2(v7, by, ay1);
    }
    for (; e + 4 <= e1; e += 4) {
        half2v v0 = *(const half2v*)(hb + (((unsigned)col[e + 0] << 8) | lo));
        half2v v1 = *(const half2v*)(hb + (((unsigned)col[e + 1] << 8) | lo));
        half2v v2 = *(const half2v*)(hb + (((unsigned)col[e + 2] << 8) | lo));
        half2v v3 = *(const half2v*)(hb + (((unsigned)col[e + 3] << 8) | lo));
        ax0 = FDOT2(v0, bx, ax0); ay0 = FDOT2(v0, by, ay0);
        ax1 = FDOT2(v1, bx, ax1); ay1 = FDOT2(v1, by, ay1);
        ax0 = FDOT2(v2, bx, ax0); ay0 = FDOT2(v2, by, ay0);
        ax1 = FDOT2(v3, bx, ax1); ay1 = FDOT2(v3, by, ay1);
    }
    for (; e < e1; ++e) {
        half2v v = *(const half2v*)(hb + (((unsigned)col[e] << 8) | lo));
        ax0 = FDOT2(v, bx, ax0); ay0 = FDOT2(v, by, ay0);
    }
    half2v vs = *(const half2v*)(hb + (((unsigned)i << 8) | lo));
    float di = dinv[i];
    float vx = di * (ax0 + ax1 + (float)vs.x) + bias[lane * 2];
    float vy = di * (ay0 + ay1 + (float)vs.y) + bias[lane * 2 + 1];
    if (do_bn_relu) {
        vx = fmaf(vx, gamma[lane * 2] * BN_RSQRT, beta[lane * 2]);
        vy = fmaf(vy, gamma[lane * 2 + 1] * BN_RSQRT, beta[lane * 2 + 1]);
        vx = vx > 0.f ? vx : 0.f;
        vy = vy > 0.f ? vy : 0.f;
    }
    half2v o = {(half_t)vx, (half_t)vy};
    *(half2v*)(out + (size_t)i * 128 + lane * 2) = o;
}

// ---------------- mean pool per graph (batch sorted) ----------------
__global__ void pool_f16(const half_t* __restrict__ h, const int* __restrict__ boffs,
                         float* __restrict__ gout) {
    int g = blockIdx.x;
    int t = threadIdx.x;  // 64 threads, 2 feats each
    int n0 = boffs[g], n1 = boffs[g + 1];
    float ax = 0.f, ay = 0.f;
    for (int n = n0; n < n1; ++n) {
        half2v v = *(const half2v*)(h + (size_t)n * 128 + t * 2);
        ax += (float)v.x;
        ay += (float)v.y;
    }
    float cnt = (float)((n1 - n0) > 1 ? (n1 - n0) : 1);
    gout[(size_t)g * 128 + t * 2] = ax / cnt;
    gout[(size_t)g * 128 + t * 2 + 1] = ay / cnt;
}

// ---------------- classifier + log_softmax ----------------
__global__ void cls_kernel(const float* __restrict__ g, const float* __restrict__ W,
                           const float* __restrict__ b, float* __restrict__ out) {
    int i = blockIdx.x * blockDim.x + threadIdx.x;
    if (i >= N_GRAPHS) return;
    float z[N_CLASS];
#pragma unroll
    for (int c = 0; c < N_CLASS; ++c) z[c] = b[c];
    for (int k = 0; k < N_HID; ++k) {
        float gv = g[(size_t)i * N_HID + k];
#pragma unroll
        for (int c = 0; c < N_CLASS; ++c) z[c] = fmaf(gv, W[k * N_CLASS + c], z[c]);
    }
    float m = z[0];
#pragma unroll
    for (int c = 1; c < N_CLASS; ++c) m = fmaxf(m, z[c]);
    float s = 0.f;
#pragma unroll
    for (int c = 0; c < N_CLASS; ++c) s += expf(z[c] - m);
    float l = logf(s);
#pragma unroll
    for (int c = 0; c < N_CLASS; ++c) out[(size_t)i * N_CLASS + c] = z[c] - m - l;
}

extern "C" void kernel_launch(void* const* d_in, const int* in_sizes, int n_in,
                              void* d_out, int out_size, void* d_ws, size_t ws_size,
                              hipStream_t stream) {
    const float* x     = (const float*)d_in[0];
    const int*   ei    = (const int*)d_in[1];
    const int*   batch = (const int*)d_in[2];
    const float* W1    = (const float*)d_in[3];
    const float* b1    = (const float*)d_in[4];
    const float* gamma = (const float*)d_in[5];
    const float* beta  = (const float*)d_in[6];
    const float* W2    = (const float*)d_in[7];
    const float* b2    = (const float*)d_in[8];
    const float* clsW  = (const float*)d_in[9];
    const float* clsb  = (const float*)d_in[10];

    const int N = in_sizes[0] / N_FEAT;   // 100000
    const int E = in_sizes[1] / 2;        // 1600000
    const int* src = ei;
    const int* dst = ei + E;

    // -------- workspace carve --------
    half_t* BA = (half_t*)d_ws;                       // N*128 f16
    half_t* BB = BA + (size_t)N * 128;                // N*128 f16
    half_t* Wt1 = BB + (size_t)N * 128;               // 16384 f16
    half_t* Wt2 = Wt1 + 16384;                        // 16384 f16
    int*   col     = (int*)(Wt2 + 16384);             // E
    int*   rowptr  = col + E;                         // N+1 (+pad)
    int*   deg     = rowptr + (N + 4);                // N
    int*   fillptr = deg + N;                         // N
    float* dinv    = (float*)(fillptr + N);           // N
    int*   boffs   = (int*)(dinv + N);                // 513 (+pad)
    int*   bsums   = boffs + N_GRAPHS + 4;            // ceil(N/256)=391 (+pad)

    hipMemsetAsync(deg, 0, (size_t)N * 4, stream);

    const int nb = (N + 255) / 256;                       // 391
    const int nchunks = (E + CSR_CHUNK - 1) / CSR_CHUNK;  // 391

    deg_xcd<<<nchunks * 8, 256, 0, stream>>>(dst, deg, nchunks, E);
    boffs_kernel<<<nb, 256, 0, stream>>>(batch, boffs, N);
    block_reduce<<<nb, 256, 0, stream>>>(deg, bsums, N);
    scan_small<<<1, 1024, 0, stream>>>(bsums, nb);
    scan_final<<<nb, 256, 0, stream>>>(deg, bsums, rowptr, fillptr, dinv, N, E);
    csr_fill_xcd<<<nchunks * 8, 256, 0, stream>>>(src, dst, fillptr, col, nchunks, E);

    prep_w<<<128, 256, 0, stream>>>(W1, Wt1, W2, Wt2);

    // layer 1: BA = dinv*(x@W1); BB = agg(BA)+b1, BN, ReLU
    gemm1_mfma<<<(N + 63) / 64, 256, 0, stream>>>(x, Wt1, dinv, BA, N);
    agg_f16<<<(N + 3) / 4, 256, 0, stream>>>(BA, BB, col, rowptr, dinv, b1, gamma, beta, N, 1);
    // layer 2: BA = dinv*(BB@W2); BB = agg(BA)+b2
    gemm2_mfma<<<(N + 63) / 64, 256, 0, stream>>>(BB, Wt2, dinv, BA, N);
    agg_f16<<<(N + 3) / 4, 256, 0, stream>>>(BA, BB, col, rowptr, dinv, b2, gamma, beta, N, 0);

    float* out = (float*)d_out;
    float* gsec = out + (size_t)N_GRAPHS * N_CLASS;
    pool_f16<<<N_GRAPHS, 64, 0, stream>>>(BB, boffs, gsec);
    cls_kernel<<<2, 256, 0, stream>>>(gsec, clsW, clsb, out);
}

// Round 5
// 502.128 us; speedup vs baseline: 2.3246x; 1.0586x over previous
//
#include <hip/hip_runtime.h>
#include <hip/hip_bf16.h>

#define N_NODES 100000
#define N_EDGES 1600000
#define N_FEAT 128
#define N_HID 128
#define N_CLASS 10
#define N_GRAPHS 512
// 1/sqrt(1 + 1e-5)
#define BN_RSQRT 0.9999950000374997f

// node-range partitioning for LDS histograms: 8 ranges x 12500 nodes
#define NRANGE 12500
#define NCHUNK 64

typedef _Float16 half_t;
typedef __attribute__((ext_vector_type(2))) _Float16 half2v;
typedef __attribute__((ext_vector_type(4))) _Float16 half4v;
typedef __attribute__((ext_vector_type(8))) _Float16 half8v;
typedef __attribute__((ext_vector_type(4))) float floatx4;

#if defined(__has_builtin)
#if __has_builtin(__builtin_amdgcn_fdot2)
#define HAVE_FDOT2 1
#endif
#endif
#ifdef HAVE_FDOT2
#define FDOT2(a, b, c) __builtin_amdgcn_fdot2((a), (b), (c), false)
#else
#define FDOT2(a, b, c) ((c) + (float)(a).x * (float)(b).x + (float)(a).y * (float)(b).y)
#endif

// ---------------- phase 1: per-(range,chunk) LDS histogram, no global atomics ----
// grid = NCHUNK*8; r = blockIdx&7 (XCD-stable), c = blockIdx>>3.
__global__ __launch_bounds__(256) void hist_xcd(
    const int* __restrict__ dst, int* __restrict__ partial, int chunkE, int E)
{
    __shared__ int h[NRANGE];
    int r = blockIdx.x & 7;
    int c = blockIdx.x >> 3;
    for (int i = threadIdx.x; i < NRANGE; i += 256) h[i] = 0;
    __syncthreads();
    int base = c * chunkE;
    int end = base + chunkE < E ? base + chunkE : E;
    for (int e = base + threadIdx.x; e < end; e += 256) {
        int d = dst[e];
        int rr = (d * 8) / N_NODES;   // magic-mul, compile-time N
        if (rr == r) atomicAdd(&h[d - rr * NRANGE], 1);
    }
    __syncthreads();
    int* slice = partial + (size_t)(r * NCHUNK + c) * NRANGE;
    for (int i = threadIdx.x; i < NRANGE; i += 256) slice[i] = h[i];
}

// ---------------- deg[d] = sum_c partial[r][c][dl]; also dinv ----------------
__global__ void deg_reduce(const int* __restrict__ partial, int* __restrict__ deg,
                           float* __restrict__ dinv, int n) {
    int i = blockIdx.x * 256 + threadIdx.x;
    if (i >= n) return;
    int rr = (i * 8) / N_NODES;
    int dl = i - rr * NRANGE;
    const int* p = partial + (size_t)rr * NCHUNK * NRANGE + dl;
    int s = 0;
#pragma unroll 8
    for (int c = 0; c < NCHUNK; ++c) s += p[(size_t)c * NRANGE];
    deg[i] = s;
    dinv[i] = rsqrtf((float)s + 1.0f);  // +1 = self loop
}

// ---------------- multi-block exclusive scan ----------------
__global__ void block_reduce(const int* __restrict__ in, int* __restrict__ bsums, int n) {
    __shared__ int s[256];
    int t = threadIdx.x;
    int i = blockIdx.x * 256 + t;
    s[t] = (i < n) ? in[i] : 0;
    __syncthreads();
    for (int off = 128; off > 0; off >>= 1) {
        if (t < off) s[t] += s[t + off];
        __syncthreads();
    }
    if (t == 0) bsums[blockIdx.x] = s[0];
}

__global__ void scan_small(int* __restrict__ bsums, int nb) {
    __shared__ int buf[1024];
    int t = threadIdx.x;
    int v = (t < nb) ? bsums[t] : 0;
    buf[t] = v;
    __syncthreads();
    for (int off = 1; off < 1024; off <<= 1) {
        int x = (t >= off) ? buf[t - off] : 0;
        __syncthreads();
        buf[t] += x;
        __syncthreads();
    }
    if (t < nb) bsums[t] = buf[t] - v;
}

__global__ void scan_final(const int* __restrict__ in, const int* __restrict__ bsums,
                           int* __restrict__ rowptr, int n, int total) {
    __shared__ int s[256];
    int t = threadIdx.x;
    int i = blockIdx.x * 256 + t;
    int v = (i < n) ? in[i] : 0;
    s[t] = v;
    __syncthreads();
    for (int off = 1; off < 256; off <<= 1) {
        int x = (t >= off) ? s[t - off] : 0;
        __syncthreads();
        s[t] += x;
        __syncthreads();
    }
    if (i < n) rowptr[i] = bsums[blockIdx.x] + s[t] - v;
    if (i == 0) rowptr[n] = total;
}

// ---------------- exclusive scan along chunks, seeded with rowptr (in-place) -----
__global__ void chunkoff_kernel(int* __restrict__ partial, const int* __restrict__ rowptr,
                                int n) {
    int i = blockIdx.x * 256 + threadIdx.x;
    if (i >= n) return;
    int rr = (i * 8) / N_NODES;
    int dl = i - rr * NRANGE;
    int* p = partial + (size_t)rr * NCHUNK * NRANGE + dl;
    int running = rowptr[i];
    for (int c = 0; c < NCHUNK; ++c) {
        int t = p[(size_t)c * NRANGE];
        p[(size_t)c * NRANGE] = running;
        running += t;
    }
}

// ---------------- phase 2: fill col via LDS offset-bump, no global atomics -------
__global__ __launch_bounds__(256) void fill_lds(
    const int* __restrict__ src, const int* __restrict__ dst,
    const int* __restrict__ partial, int* __restrict__ col, int chunkE, int E)
{
    __shared__ int off[NRANGE];
    int r = blockIdx.x & 7;
    int c = blockIdx.x >> 3;
    const int* slice = partial + (size_t)(r * NCHUNK + c) * NRANGE;
    for (int i = threadIdx.x; i < NRANGE; i += 256) off[i] = slice[i];
    __syncthreads();
    int base = c * chunkE;
    int end = base + chunkE < E ? base + chunkE : E;
    for (int e = base + threadIdx.x; e < end; e += 256) {
        int d = dst[e];
        int rr = (d * 8) / N_NODES;
        if (rr == r) {
            int pos = atomicAdd(&off[d - rr * NRANGE], 1);
            col[pos] = src[e];
        }
    }
}

// ---------------- graph offsets from sorted batch (boundary detect) --------------
__global__ void boffs_kernel(const int* __restrict__ batch, int* __restrict__ boffs, int n) {
    int i = blockIdx.x * 256 + threadIdx.x;
    if (i >= n) return;
    int b = batch[i];
    int prev = (i == 0) ? -1 : batch[i - 1];
    for (int g = prev + 1; g <= b; ++g) boffs[g] = i;
    if (i == n - 1)
        for (int g = b + 1; g <= N_GRAPHS; ++g) boffs[g] = n;
}

// ---------------- both W[128x128] f32 -> Wt f16 transposed, one launch ----------
__global__ void prep_w(const float* __restrict__ W1, half_t* __restrict__ Wt1,
                       const float* __restrict__ W2, half_t* __restrict__ Wt2) {
    int i = blockIdx.x * 256 + threadIdx.x;  // 0..32767
    const float* W = (i < 16384) ? W1 : W2;
    half_t* Wt = (i < 16384) ? Wt1 : Wt2;
    int j = i & 16383;
    int c = j >> 7, k = j & 127;
    Wt[(size_t)c * 128 + k] = (half_t)W[(size_t)k * 128 + c];
}

// ---------------- MFMA GEMM (f32 input): Y = dinv[row]*(X@W), f16 out -----------
__global__ __launch_bounds__(256) void gemm1_mfma(
    const float* __restrict__ X, const half_t* __restrict__ Wt,
    const float* __restrict__ dinv, half_t* __restrict__ Y, int nrows)
{
    int wave = threadIdx.x >> 6;
    int lane = threadIdx.x & 63;
    int n16  = lane & 15;
    int quad = lane >> 4;
    int r0 = blockIdx.x * 64 + wave * 16;
    if (r0 >= nrows) return;
    int row = r0 + n16;
    const float4* xrow = (const float4*)(X + (size_t)row * 128);
    half8v a[4];
#pragma unroll
    for (int kc = 0; kc < 4; ++kc) {
        float4 f0 = xrow[kc * 8 + quad * 2];
        float4 f1 = xrow[kc * 8 + quad * 2 + 1];
        half8v t = {(half_t)f0.x, (half_t)f0.y, (half_t)f0.z, (half_t)f0.w,
                    (half_t)f1.x, (half_t)f1.y, (half_t)f1.z, (half_t)f1.w};
        a[kc] = t;
    }
    float dr = dinv[row];
#pragma unroll
    for (int c = 0; c < 8; ++c) {
        const half8v* wrow = (const half8v*)(Wt + (size_t)(c * 16 + n16) * 128);
        floatx4 acc = {0.f, 0.f, 0.f, 0.f};
        acc = __builtin_amdgcn_mfma_f32_16x16x32_f16(wrow[0 * 4 + quad], a[0], acc, 0, 0, 0);
        acc = __builtin_amdgcn_mfma_f32_16x16x32_f16(wrow[1 * 4 + quad], a[1], acc, 0, 0, 0);
        acc = __builtin_amdgcn_mfma_f32_16x16x32_f16(wrow[2 * 4 + quad], a[2], acc, 0, 0, 0);
        acc = __builtin_amdgcn_mfma_f32_16x16x32_f16(wrow[3 * 4 + quad], a[3], acc, 0, 0, 0);
        half4v o = {(half_t)(acc[0] * dr), (half_t)(acc[1] * dr),
                    (half_t)(acc[2] * dr), (half_t)(acc[3] * dr)};
        *(half4v*)(Y + (size_t)row * 128 + c * 16 + quad * 4) = o;
    }
}

// ---------------- MFMA GEMM (f16 input): Y = dinv[row]*(X@W), f16 out -----------
__global__ __launch_bounds__(256) void gemm2_mfma(
    const half_t* __restrict__ X, const half_t* __restrict__ Wt,
    const float* __restrict__ dinv, half_t* __restrict__ Y, int nrows)
{
    int wave = threadIdx.x >> 6;
    int lane = threadIdx.x & 63;
    int n16  = lane & 15;
    int quad = lane >> 4;
    int r0 = blockIdx.x * 64 + wave * 16;
    if (r0 >= nrows) return;
    int row = r0 + n16;
    const half8v* xrow = (const half8v*)(X + (size_t)row * 128);
    half8v a0 = xrow[0 * 4 + quad];
    half8v a1 = xrow[1 * 4 + quad];
    half8v a2 = xrow[2 * 4 + quad];
    half8v a3 = xrow[3 * 4 + quad];
    float dr = dinv[row];
#pragma unroll
    for (int c = 0; c < 8; ++c) {
        const half8v* wrow = (const half8v*)(Wt + (size_t)(c * 16 + n16) * 128);
        floatx4 acc = {0.f, 0.f, 0.f, 0.f};
        acc = __builtin_amdgcn_mfma_f32_16x16x32_f16(wrow[0 * 4 + quad], a0, acc, 0, 0, 0);
        acc = __builtin_amdgcn_mfma_f32_16x16x32_f16(wrow[1 * 4 + quad], a1, acc, 0, 0, 0);
        acc = __builtin_amdgcn_mfma_f32_16x16x32_f16(wrow[2 * 4 + quad], a2, acc, 0, 0, 0);
        acc = __builtin_amdgcn_mfma_f32_16x16x32_f16(wrow[3 * 4 + quad], a3, acc, 0, 0, 0);
        half4v o = {(half_t)(acc[0] * dr), (half_t)(acc[1] * dr),
                    (half_t)(acc[2] * dr), (half_t)(acc[3] * dr)};
        *(half4v*)(Y + (size_t)row * 128 + c * 16 + quad * 4) = o;
    }
}

// ---------------- aggregation over pre-scaled hs = dinv*h ----------------------
__global__ __launch_bounds__(256) void agg_f16(
    const half_t* __restrict__ hs, half_t* __restrict__ out,
    const int* __restrict__ col, const int* __restrict__ rowptr,
    const float* __restrict__ dinv, const float* __restrict__ bias,
    const float* __restrict__ gamma, const float* __restrict__ beta,
    int nnodes, int do_bn_relu)
{
    int wave = threadIdx.x >> 6;
    int lane = threadIdx.x & 63;
    int i = blockIdx.x * 4 + wave;
    if (i >= nnodes) return;
    int e0 = rowptr[i], e1 = rowptr[i + 1];
    const char* hb = (const char*)hs;
    unsigned lo = (unsigned)lane << 2;
    const half2v bx = {(half_t)1.0f, (half_t)0.0f};
    const half2v by = {(half_t)0.0f, (half_t)1.0f};
    float ax0 = 0.f, ay0 = 0.f, ax1 = 0.f, ay1 = 0.f;
    int e = e0;
    for (; e + 8 <= e1; e += 8) {
        half2v v0 = *(const half2v*)(hb + (((unsigned)col[e + 0] << 8) | lo));
        half2v v1 = *(const half2v*)(hb + (((unsigned)col[e + 1] << 8) | lo));
        half2v v2 = *(const half2v*)(hb + (((unsigned)col[e + 2] << 8) | lo));
        half2v v3 = *(const half2v*)(hb + (((unsigned)col[e + 3] << 8) | lo));
        half2v v4 = *(const half2v*)(hb + (((unsigned)col[e + 4] << 8) | lo));
        half2v v5 = *(const half2v*)(hb + (((unsigned)col[e + 5] << 8) | lo));
        half2v v6 = *(const half2v*)(hb + (((unsigned)col[e + 6] << 8) | lo));
        half2v v7 = *(const half2v*)(hb + (((unsigned)col[e + 7] << 8) | lo));
        ax0 = FDOT2(v0, bx, ax0); ay0 = FDOT2(v0, by, ay0);
        ax1 = FDOT2(v1, bx, ax1); ay1 = FDOT2(v1, by, ay1);
        ax0 = FDOT2(v2, bx, ax0); ay0 = FDOT2(v2, by, ay0);
        ax1 = FDOT2(v3, bx, ax1); ay1 = FDOT2(v3, by, ay1);
        ax0 = FDOT2(v4, bx, ax0); ay0 = FDOT2(v4, by, ay0);
        ax1 = FDOT2(v5, bx, ax1); ay1 = FDOT2(v5, by, ay1);
        ax0 = FDOT2(v6, bx, ax0); ay0 = FDOT2(v6, by, ay0);
        ax1 = FDOT2(v7, bx, ax1); ay1 = FDOT2(v7, by, ay1);
    }
    for (; e + 4 <= e1; e += 4) {
        half2v v0 = *(const half2v*)(hb + (((unsigned)col[e + 0] << 8) | lo));
        half2v v1 = *(const half2v*)(hb + (((unsigned)col[e + 1] << 8) | lo));
        half2v v2 = *(const half2v*)(hb + (((unsigned)col[e + 2] << 8) | lo));
        half2v v3 = *(const half2v*)(hb + (((unsigned)col[e + 3] << 8) | lo));
        ax0 = FDOT2(v0, bx, ax0); ay0 = FDOT2(v0, by, ay0);
        ax1 = FDOT2(v1, bx, ax1); ay1 = FDOT2(v1, by, ay1);
        ax0 = FDOT2(v2, bx, ax0); ay0 = FDOT2(v2, by, ay0);
        ax1 = FDOT2(v3, bx, ax1); ay1 = FDOT2(v3, by, ay1);
    }
    for (; e < e1; ++e) {
        half2v v = *(const half2v*)(hb + (((unsigned)col[e] << 8) | lo));
        ax0 = FDOT2(v, bx, ax0); ay0 = FDOT2(v, by, ay0);
    }
    half2v vs = *(const half2v*)(hb + (((unsigned)i << 8) | lo));
    float di = dinv[i];
    float vx = di * (ax0 + ax1 + (float)vs.x) + bias[lane * 2];
    float vy = di * (ay0 + ay1 + (float)vs.y) + bias[lane * 2 + 1];
    if (do_bn_relu) {
        vx = fmaf(vx, gamma[lane * 2] * BN_RSQRT, beta[lane * 2]);
        vy = fmaf(vy, gamma[lane * 2 + 1] * BN_RSQRT, beta[lane * 2 + 1]);
        vx = vx > 0.f ? vx : 0.f;
        vy = vy > 0.f ? vy : 0.f;
    }
    half2v o = {(half_t)vx, (half_t)vy};
    *(half2v*)(out + (size_t)i * 128 + lane * 2) = o;
}

// ---------------- mean pool per graph (batch sorted) ----------------
__global__ void pool_f16(const half_t* __restrict__ h, const int* __restrict__ boffs,
                         float* __restrict__ gout) {
    int g = blockIdx.x;
    int t = threadIdx.x;  // 64 threads, 2 feats each
    int n0 = boffs[g], n1 = boffs[g + 1];
    float ax = 0.f, ay = 0.f;
    for (int n = n0; n < n1; ++n) {
        half2v v = *(const half2v*)(h + (size_t)n * 128 + t * 2);
        ax += (float)v.x;
        ay += (float)v.y;
    }
    float cnt = (float)((n1 - n0) > 1 ? (n1 - n0) : 1);
    gout[(size_t)g * 128 + t * 2] = ax / cnt;
    gout[(size_t)g * 128 + t * 2 + 1] = ay / cnt;
}

// ---------------- classifier + log_softmax ----------------
__global__ void cls_kernel(const float* __restrict__ g, const float* __restrict__ W,
                           const float* __restrict__ b, float* __restrict__ out) {
    int i = blockIdx.x * blockDim.x + threadIdx.x;
    if (i >= N_GRAPHS) return;
    float z[N_CLASS];
#pragma unroll
    for (int c = 0; c < N_CLASS; ++c) z[c] = b[c];
    for (int k = 0; k < N_HID; ++k) {
        float gv = g[(size_t)i * N_HID + k];
#pragma unroll
        for (int c = 0; c < N_CLASS; ++c) z[c] = fmaf(gv, W[k * N_CLASS + c], z[c]);
    }
    float m = z[0];
#pragma unroll
    for (int c = 1; c < N_CLASS; ++c) m = fmaxf(m, z[c]);
    float s = 0.f;
#pragma unroll
    for (int c = 0; c < N_CLASS; ++c) s += expf(z[c] - m);
    float l = logf(s);
#pragma unroll
    for (int c = 0; c < N_CLASS; ++c) out[(size_t)i * N_CLASS + c] = z[c] - m - l;
}

extern "C" void kernel_launch(void* const* d_in, const int* in_sizes, int n_in,
                              void* d_out, int out_size, void* d_ws, size_t ws_size,
                              hipStream_t stream) {
    const float* x     = (const float*)d_in[0];
    const int*   ei    = (const int*)d_in[1];
    const int*   batch = (const int*)d_in[2];
    const float* W1    = (const float*)d_in[3];
    const float* b1    = (const float*)d_in[4];
    const float* gamma = (const float*)d_in[5];
    const float* beta  = (const float*)d_in[6];
    const float* W2    = (const float*)d_in[7];
    const float* b2    = (const float*)d_in[8];
    const float* clsW  = (const float*)d_in[9];
    const float* clsb  = (const float*)d_in[10];

    const int N = in_sizes[0] / N_FEAT;   // 100000
    const int E = in_sizes[1] / 2;        // 1600000
    const int* src = ei;
    const int* dst = ei + E;

    // -------- workspace carve --------
    half_t* BA = (half_t*)d_ws;                       // N*128 f16
    half_t* BB = BA + (size_t)N * 128;                // N*128 f16
    half_t* Wt1 = BB + (size_t)N * 128;               // 16384 f16
    half_t* Wt2 = Wt1 + 16384;                        // 16384 f16
    int*   col     = (int*)(Wt2 + 16384);             // E
    int*   rowptr  = col + E;                         // N+1 (+pad)
    int*   deg     = rowptr + (N + 4);                // N
    float* dinv    = (float*)(deg + N);               // N
    int*   partial = (int*)(dinv + N);                // 8*NCHUNK*NRANGE = 6.4M ints
    int*   boffs   = partial + 8 * NCHUNK * NRANGE;   // 513 (+pad)
    int*   bsums   = boffs + N_GRAPHS + 4;            // ceil(N/256)=391 (+pad)

    const int nb = (N + 255) / 256;                   // 391
    const int chunkE = (E + NCHUNK - 1) / NCHUNK;     // 25000

    hist_xcd<<<NCHUNK * 8, 256, 0, stream>>>(dst, partial, chunkE, E);
    boffs_kernel<<<nb, 256, 0, stream>>>(batch, boffs, N);
    deg_reduce<<<nb, 256, 0, stream>>>(partial, deg, dinv, N);
    block_reduce<<<nb, 256, 0, stream>>>(deg, bsums, N);
    scan_small<<<1, 1024, 0, stream>>>(bsums, nb);
    scan_final<<<nb, 256, 0, stream>>>(deg, bsums, rowptr, N, E);
    chunkoff_kernel<<<nb, 256, 0, stream>>>(partial, rowptr, N);
    fill_lds<<<NCHUNK * 8, 256, 0, stream>>>(src, dst, partial, col, chunkE, E);

    prep_w<<<128, 256, 0, stream>>>(W1, Wt1, W2, Wt2);

    // layer 1: BA = dinv*(x@W1); BB = agg(BA)+b1, BN, ReLU
    gemm1_mfma<<<(N + 63) / 64, 256, 0, stream>>>(x, Wt1, dinv, BA, N);
    agg_f16<<<(N + 3) / 4, 256, 0, stream>>>(BA, BB, col, rowptr, dinv, b1, gamma, beta, N, 1);
    // layer 2: BA = dinv*(BB@W2); BB = agg(BA)+b2
    gemm2_mfma<<<(N + 63) / 64, 256, 0, stream>>>(BB, Wt2, dinv, BA, N);
    agg_f16<<<(N + 3) / 4, 256, 0, stream>>>(BA, BB, col, rowptr, dinv, b2, gamma, beta, N, 0);

    float* out = (float*)d_out;
    float* gsec = out + (size_t)N_GRAPHS * N_CLASS;
    pool_f16<<<N_GRAPHS, 64, 0, stream>>>(BB, boffs, gsec);
    cls_kernel<<<2, 256, 0, stream>>>(gsec, clsW, clsb, out);
}